// Round 1
// baseline (4177.488 us; speedup 1.0000x reference)
//
#include <hip/hip_runtime.h>
#include <math.h>

// Problem constants (B=8, N=4096, C=256, K=32)
constexpr int B_ = 8;
constexpr int N_ = 4096;
constexpr int C_ = 256;
constexpr int K_ = 32;
constexpr int D_ = 2 * C_;          // 512
constexpr int ROWS = B_ * N_;       // 32768

// ws layout:
//   fp  : float[ROWS * D_]   (64 MB)  feat_pos, feat = [:,0:256], pos = [:,256:512]
//   tkv : float[ROWS * 32]   (4 MB)
//   tki : int  [ROWS * 32]   (4 MB)

// ---------------------------------------------------------------------------
// Kernel 1: feat_pos = x @ W^T + bias   (fp32 tiled GEMM)
// grid (8, 512): blockIdx.x -> 64-wide d tile, blockIdx.y -> 64-row tile
// ---------------------------------------------------------------------------
__global__ __launch_bounds__(256) void k_gemm_bias(
    const float* __restrict__ x, const float* __restrict__ W,
    const float* __restrict__ bias, float* __restrict__ fp)
{
    __shared__ float At[256 * 68];   // A^T[k][row], pad 68
    __shared__ float Bt[64 * 68];    // B^T[kk][col]

    const int tid = threadIdx.x;
    const int w = tid >> 6, l = tid & 63;
    const int tr = tid >> 4, tc = tid & 15;
    const int d0 = blockIdx.x * 64;
    const int r0 = blockIdx.y * 64;

    // Stage A^T: 64 x-rows, K=256. One row per wave-iteration, coalesced 1 KB.
    #pragma unroll 4
    for (int i = 0; i < 16; ++i) {
        int rl = w * 16 + i;
        float4 v = *(const float4*)&x[(size_t)(r0 + rl) * C_ + 4 * l];
        At[(4 * l + 0) * 68 + rl] = v.x;
        At[(4 * l + 1) * 68 + rl] = v.y;
        At[(4 * l + 2) * 68 + rl] = v.z;
        At[(4 * l + 3) * 68 + rl] = v.w;
    }

    float4 acc0 = {0,0,0,0}, acc1 = {0,0,0,0}, acc2 = {0,0,0,0}, acc3 = {0,0,0,0};

    for (int kc = 0; kc < 4; ++kc) {
        __syncthreads();
        // Stage B^T chunk: W rows d0..d0+63, k slice kc*64..+63
        #pragma unroll
        for (int pass = 0; pass < 4; ++pass) {
            int cl = pass * 16 + w * 4 + (l >> 4);
            int kk = (l & 15) * 4;
            float4 v = *(const float4*)&W[(size_t)(d0 + cl) * C_ + kc * 64 + kk];
            Bt[(kk + 0) * 68 + cl] = v.x;
            Bt[(kk + 1) * 68 + cl] = v.y;
            Bt[(kk + 2) * 68 + cl] = v.z;
            Bt[(kk + 3) * 68 + cl] = v.w;
        }
        __syncthreads();
        #pragma unroll 8
        for (int kk = 0; kk < 64; ++kk) {
            float4 a = *(const float4*)&At[(kc * 64 + kk) * 68 + 4 * tr];
            float4 b = *(const float4*)&Bt[kk * 68 + 4 * tc];
            acc0.x = fmaf(a.x, b.x, acc0.x); acc0.y = fmaf(a.x, b.y, acc0.y);
            acc0.z = fmaf(a.x, b.z, acc0.z); acc0.w = fmaf(a.x, b.w, acc0.w);
            acc1.x = fmaf(a.y, b.x, acc1.x); acc1.y = fmaf(a.y, b.y, acc1.y);
            acc1.z = fmaf(a.y, b.z, acc1.z); acc1.w = fmaf(a.y, b.w, acc1.w);
            acc2.x = fmaf(a.z, b.x, acc2.x); acc2.y = fmaf(a.z, b.y, acc2.y);
            acc2.z = fmaf(a.z, b.z, acc2.z); acc2.w = fmaf(a.z, b.w, acc2.w);
            acc3.x = fmaf(a.w, b.x, acc3.x); acc3.y = fmaf(a.w, b.y, acc3.y);
            acc3.z = fmaf(a.w, b.z, acc3.z); acc3.w = fmaf(a.w, b.w, acc3.w);
        }
    }

    float4 bv = *(const float4*)&bias[d0 + 4 * tc];
    float4 o;
    o.x = acc0.x + bv.x; o.y = acc0.y + bv.y; o.z = acc0.z + bv.z; o.w = acc0.w + bv.w;
    *(float4*)&fp[(size_t)(r0 + 4 * tr + 0) * D_ + d0 + 4 * tc] = o;
    o.x = acc1.x + bv.x; o.y = acc1.y + bv.y; o.z = acc1.z + bv.z; o.w = acc1.w + bv.w;
    *(float4*)&fp[(size_t)(r0 + 4 * tr + 1) * D_ + d0 + 4 * tc] = o;
    o.x = acc2.x + bv.x; o.y = acc2.y + bv.y; o.z = acc2.z + bv.z; o.w = acc2.w + bv.w;
    *(float4*)&fp[(size_t)(r0 + 4 * tr + 2) * D_ + d0 + 4 * tc] = o;
    o.x = acc3.x + bv.x; o.y = acc3.y + bv.y; o.z = acc3.z + bv.z; o.w = acc3.w + bv.w;
    *(float4*)&fp[(size_t)(r0 + 4 * tr + 3) * D_ + d0 + 4 * tc] = o;
}

// ---------------------------------------------------------------------------
// Kernel 2: normalize pos rows in place. One wave per row.
// ---------------------------------------------------------------------------
__global__ __launch_bounds__(256) void k_norm(float* __restrict__ fp)
{
    const int w = threadIdx.x >> 6, l = threadIdx.x & 63;
    const int row = blockIdx.x * 4 + w;
    float* p = &fp[(size_t)row * D_ + C_];
    float4 v = *(float4*)&p[4 * l];
    float s = v.x * v.x + v.y * v.y + v.z * v.z + v.w * v.w;
    #pragma unroll
    for (int m = 1; m < 64; m <<= 1) s += __shfl_xor(s, m);
    float scale = 1.0f / fmaxf(sqrtf(s), 1e-12f);
    v.x *= scale; v.y *= scale; v.z *= scale; v.w *= scale;
    *(float4*)&p[4 * l] = v;
}

// ---------------------------------------------------------------------------
// Kernel 3: fused sim (pos @ pos^T per batch, fp32) + streaming top-32.
// grid 512: one block per 64-row tile. Loops over 64 column tiles of 64.
// ---------------------------------------------------------------------------
__global__ __launch_bounds__(256) void k_simtopk(
    const float* __restrict__ fp, float* __restrict__ tkv, int* __restrict__ tki)
{
    __shared__ float At[256 * 68];   // pos^T of this block's 64 rows
    __shared__ float Bt[64 * 68];    // pos^T chunk of 64 cols x 64 k
    __shared__ float Sm[64 * 68];    // 64x64 sim tile
    __shared__ float Tv[64 * 33];    // top-32 values per row (pad 33)
    __shared__ int   Ti[64 * 33];    // top-32 indices per row

    const int tid = threadIdx.x;
    const int w = tid >> 6, l = tid & 63;
    const int tr = tid >> 4, tc = tid & 15;
    const int r0 = blockIdx.x * 64;
    const int batch = r0 >> 12;               // / 4096
    const size_t bbase = (size_t)batch * N_;

    // Stage A^T from pos rows r0..r0+63
    #pragma unroll 4
    for (int i = 0; i < 16; ++i) {
        int rl = w * 16 + i;
        float4 v = *(const float4*)&fp[(size_t)(r0 + rl) * D_ + C_ + 4 * l];
        At[(4 * l + 0) * 68 + rl] = v.x;
        At[(4 * l + 1) * 68 + rl] = v.y;
        At[(4 * l + 2) * 68 + rl] = v.z;
        At[(4 * l + 3) * 68 + rl] = v.w;
    }
    if (tid < 64) {
        #pragma unroll
        for (int s = 0; s < 32; ++s) { Tv[tid * 33 + s] = -1e30f; Ti[tid * 33 + s] = 0; }
    }
    float thr = -1e30f;   // current min of the 32 (owner lanes only)
    int minpos = 0;

    for (int ct = 0; ct < 64; ++ct) {
        const int c0 = ct * 64;
        float4 acc0 = {0,0,0,0}, acc1 = {0,0,0,0}, acc2 = {0,0,0,0}, acc3 = {0,0,0,0};

        for (int kc = 0; kc < 4; ++kc) {
            __syncthreads();   // Bt reuse + (tile start) orders previous scan reads
            #pragma unroll
            for (int pass = 0; pass < 4; ++pass) {
                int cl = pass * 16 + w * 4 + (l >> 4);
                int kk = (l & 15) * 4;
                float4 v = *(const float4*)&fp[(bbase + c0 + cl) * D_ + C_ + kc * 64 + kk];
                Bt[(kk + 0) * 68 + cl] = v.x;
                Bt[(kk + 1) * 68 + cl] = v.y;
                Bt[(kk + 2) * 68 + cl] = v.z;
                Bt[(kk + 3) * 68 + cl] = v.w;
            }
            __syncthreads();
            #pragma unroll 8
            for (int kk = 0; kk < 64; ++kk) {
                float4 a = *(const float4*)&At[(kc * 64 + kk) * 68 + 4 * tr];
                float4 b = *(const float4*)&Bt[kk * 68 + 4 * tc];
                acc0.x = fmaf(a.x, b.x, acc0.x); acc0.y = fmaf(a.x, b.y, acc0.y);
                acc0.z = fmaf(a.x, b.z, acc0.z); acc0.w = fmaf(a.x, b.w, acc0.w);
                acc1.x = fmaf(a.y, b.x, acc1.x); acc1.y = fmaf(a.y, b.y, acc1.y);
                acc1.z = fmaf(a.y, b.z, acc1.z); acc1.w = fmaf(a.y, b.w, acc1.w);
                acc2.x = fmaf(a.z, b.x, acc2.x); acc2.y = fmaf(a.z, b.y, acc2.y);
                acc2.z = fmaf(a.z, b.z, acc2.z); acc2.w = fmaf(a.z, b.w, acc2.w);
                acc3.x = fmaf(a.w, b.x, acc3.x); acc3.y = fmaf(a.w, b.y, acc3.y);
                acc3.z = fmaf(a.w, b.z, acc3.z); acc3.w = fmaf(a.w, b.w, acc3.w);
            }
        }

        // Write 64x64 sim tile to LDS
        *(float4*)&Sm[(4 * tr + 0) * 68 + 4 * tc] = acc0;
        *(float4*)&Sm[(4 * tr + 1) * 68 + 4 * tc] = acc1;
        *(float4*)&Sm[(4 * tr + 2) * 68 + 4 * tc] = acc2;
        *(float4*)&Sm[(4 * tr + 3) * 68 + 4 * tc] = acc3;
        __syncthreads();

        // Streaming top-32 update: one owner lane per row.
        if (tid < 64) {
            const int base = tid * 68;
            const int tb = tid * 33;
            #pragma unroll 4
            for (int cc = 0; cc < 16; ++cc) {
                float4 v = *(const float4*)&Sm[base + 4 * cc];
                #pragma unroll
                for (int j = 0; j < 4; ++j) {
                    float val = (j == 0) ? v.x : (j == 1) ? v.y : (j == 2) ? v.z : v.w;
                    if (val > thr) {   // strict >  => keeps earliest index on ties (jax semantics)
                        Tv[tb + minpos] = val;
                        Ti[tb + minpos] = c0 + 4 * cc + j;
                        float mn = 1e30f; int mp = 0;
                        for (int s = 0; s < 32; ++s) {
                            float u = Tv[tb + s];
                            if (u < mn) { mn = u; mp = s; }
                        }
                        thr = mn; minpos = mp;
                    }
                }
            }
        }
        // next tile's first __syncthreads orders these scan reads vs Sm/Bt writes
    }

    __syncthreads();
    if (tid < 64) {
        const int row = r0 + tid;
        const int tb = tid * 33;
        #pragma unroll
        for (int s = 0; s < 32; ++s) {
            tkv[(size_t)row * 32 + s] = Tv[tb + s];
            tki[(size_t)row * 32 + s] = Ti[tb + s];
        }
    }
}

// ---------------------------------------------------------------------------
// Kernel 4: softmax over top-32 + gather feat + weighted sum -> out
// grid 32768: one block per row, one thread per channel.
// ---------------------------------------------------------------------------
__global__ __launch_bounds__(256) void k_out(
    const float* __restrict__ fp, const float* __restrict__ tkv,
    const int* __restrict__ tki, float* __restrict__ out)
{
    __shared__ float attn[32];
    __shared__ int   sid[32];
    const int row = blockIdx.x;
    const int batch = row >> 12;
    const int tid = threadIdx.x;

    if (tid < 32) {
        float v = tkv[(size_t)row * 32 + tid];
        float m = v;
        #pragma unroll
        for (int s = 16; s >= 1; s >>= 1) m = fmaxf(m, __shfl_xor(m, s));
        float e = expf(v - m);
        float sum = e;
        #pragma unroll
        for (int s = 16; s >= 1; s >>= 1) sum += __shfl_xor(sum, s);
        attn[tid] = e / sum;
        sid[tid]  = tki[(size_t)row * 32 + tid];
    }
    __syncthreads();

    const float* featb = fp + (size_t)batch * N_ * D_;
    float acc = 0.0f;
    #pragma unroll 8
    for (int k = 0; k < 32; ++k)
        acc = fmaf(attn[k], featb[(size_t)sid[k] * D_ + tid], acc);
    out[(size_t)row * C_ + tid] = acc;
}

// ---------------------------------------------------------------------------
extern "C" void kernel_launch(void* const* d_in, const int* in_sizes, int n_in,
                              void* d_out, int out_size, void* d_ws, size_t ws_size,
                              hipStream_t stream)
{
    const float* x    = (const float*)d_in[0];
    const float* W    = (const float*)d_in[1];
    const float* bias = (const float*)d_in[2];
    // d_in[3] = k (=32), compile-time constant here.

    float* fp  = (float*)d_ws;                      // ROWS * D_
    float* tkv = fp + (size_t)ROWS * D_;            // ROWS * 32
    int*   tki = (int*)(tkv + (size_t)ROWS * 32);   // ROWS * 32
    float* out = (float*)d_out;

    k_gemm_bias<<<dim3(D_ / 64, ROWS / 64), 256, 0, stream>>>(x, W, bias, fp);
    k_norm<<<ROWS / 4, 256, 0, stream>>>(fp);
    k_simtopk<<<ROWS / 64, 256, 0, stream>>>(fp, tkv, tki);
    k_out<<<ROWS, 256, 0, stream>>>(fp, tkv, tki, out);
}

// Round 2
// 2737.563 us; speedup vs baseline: 1.5260x; 1.5260x over previous
//
#include <hip/hip_runtime.h>
#include <math.h>

// Problem constants (B=8, N=4096, C=256, K=32)
constexpr int B_ = 8;
constexpr int N_ = 4096;
constexpr int C_ = 256;
constexpr int K_ = 32;
constexpr int D_ = 2 * C_;          // 512
constexpr int ROWS = B_ * N_;       // 32768

// ws layout:
//   fp  : float[ROWS * D_]   (64 MB)  feat_pos, feat = [:,0:256], pos = [:,256:512]
//   tkv : float[ROWS * 32]   (4 MB)
//   tki : int  [ROWS * 32]   (4 MB)

// ---------------------------------------------------------------------------
// Kernel 1: feat_pos = x @ W^T + bias   (fp32 tiled GEMM)
// 64x64 output tile, k staged in 64-chunks, k-major LDS (no transpose conflicts:
// lane index walks the row/col dim -> d(addr)/d(lane)=1).
// ---------------------------------------------------------------------------
__global__ __launch_bounds__(256, 4) void k_gemm_bias(
    const float* __restrict__ x, const float* __restrict__ W,
    const float* __restrict__ bias, float* __restrict__ fp)
{
    __shared__ float At[64 * 64];   // [kk][row]
    __shared__ float Bt[64 * 64];   // [kk][dcol]

    const int tid = threadIdx.x;
    const int w = tid >> 6, l = tid & 63;
    const int tr = tid >> 4, tc = tid & 15;
    const int d0 = blockIdx.x * 64;
    const int r0 = blockIdx.y * 64;

    float4 acc0 = {0,0,0,0}, acc1 = {0,0,0,0}, acc2 = {0,0,0,0}, acc3 = {0,0,0,0};

    for (int kc = 0; kc < 4; ++kc) {
        __syncthreads();
        // lane l owns row/col l; wave w covers k sub-chunk w*16..w*16+15
        #pragma unroll
        for (int i = 0; i < 4; ++i) {
            const int kloc = w * 16 + 4 * i;
            float4 a = *(const float4*)&x[(size_t)(r0 + l) * C_ + kc * 64 + kloc];
            At[(kloc + 0) * 64 + l] = a.x;
            At[(kloc + 1) * 64 + l] = a.y;
            At[(kloc + 2) * 64 + l] = a.z;
            At[(kloc + 3) * 64 + l] = a.w;
            float4 b = *(const float4*)&W[(size_t)(d0 + l) * C_ + kc * 64 + kloc];
            Bt[(kloc + 0) * 64 + l] = b.x;
            Bt[(kloc + 1) * 64 + l] = b.y;
            Bt[(kloc + 2) * 64 + l] = b.z;
            Bt[(kloc + 3) * 64 + l] = b.w;
        }
        __syncthreads();
        #pragma unroll 8
        for (int kk = 0; kk < 64; ++kk) {
            float4 a = *(const float4*)&At[kk * 64 + 4 * tr];
            float4 b = *(const float4*)&Bt[kk * 64 + 4 * tc];
            acc0.x = fmaf(a.x, b.x, acc0.x); acc0.y = fmaf(a.x, b.y, acc0.y);
            acc0.z = fmaf(a.x, b.z, acc0.z); acc0.w = fmaf(a.x, b.w, acc0.w);
            acc1.x = fmaf(a.y, b.x, acc1.x); acc1.y = fmaf(a.y, b.y, acc1.y);
            acc1.z = fmaf(a.y, b.z, acc1.z); acc1.w = fmaf(a.y, b.w, acc1.w);
            acc2.x = fmaf(a.z, b.x, acc2.x); acc2.y = fmaf(a.z, b.y, acc2.y);
            acc2.z = fmaf(a.z, b.z, acc2.z); acc2.w = fmaf(a.z, b.w, acc2.w);
            acc3.x = fmaf(a.w, b.x, acc3.x); acc3.y = fmaf(a.w, b.y, acc3.y);
            acc3.z = fmaf(a.w, b.z, acc3.z); acc3.w = fmaf(a.w, b.w, acc3.w);
        }
    }

    float4 bv = *(const float4*)&bias[d0 + 4 * tc];
    float4 o;
    o.x = acc0.x + bv.x; o.y = acc0.y + bv.y; o.z = acc0.z + bv.z; o.w = acc0.w + bv.w;
    *(float4*)&fp[(size_t)(r0 + 4 * tr + 0) * D_ + d0 + 4 * tc] = o;
    o.x = acc1.x + bv.x; o.y = acc1.y + bv.y; o.z = acc1.z + bv.z; o.w = acc1.w + bv.w;
    *(float4*)&fp[(size_t)(r0 + 4 * tr + 1) * D_ + d0 + 4 * tc] = o;
    o.x = acc2.x + bv.x; o.y = acc2.y + bv.y; o.z = acc2.z + bv.z; o.w = acc2.w + bv.w;
    *(float4*)&fp[(size_t)(r0 + 4 * tr + 2) * D_ + d0 + 4 * tc] = o;
    o.x = acc3.x + bv.x; o.y = acc3.y + bv.y; o.z = acc3.z + bv.z; o.w = acc3.w + bv.w;
    *(float4*)&fp[(size_t)(r0 + 4 * tr + 3) * D_ + d0 + 4 * tc] = o;
}

// ---------------------------------------------------------------------------
// Kernel 2: normalize pos rows in place. One wave per row.
// ---------------------------------------------------------------------------
__global__ __launch_bounds__(256) void k_norm(float* __restrict__ fp)
{
    const int w = threadIdx.x >> 6, l = threadIdx.x & 63;
    const int row = blockIdx.x * 4 + w;
    float* p = &fp[(size_t)row * D_ + C_];
    float4 v = *(float4*)&p[4 * l];
    float s = v.x * v.x + v.y * v.y + v.z * v.z + v.w * v.w;
    #pragma unroll
    for (int m = 1; m < 64; m <<= 1) s += __shfl_xor(s, m);
    float scale = 1.0f / fmaxf(sqrtf(s), 1e-12f);
    v.x *= scale; v.y *= scale; v.z *= scale; v.w *= scale;
    *(float4*)&p[4 * l] = v;
}

// ---------------------------------------------------------------------------
// Kernel 3: fused sim (pos @ pos^T per batch, fp32) + streaming top-32.
// 64-row block, 64-col tiles. A re-staged per (ct,kc) chunk (L2-hot) so LDS
// stays at 49 KB -> 3 blocks/CU. At buffer reused for the 64x64 sim tile.
// ---------------------------------------------------------------------------
__global__ __launch_bounds__(256, 3) void k_simtopk(
    const float* __restrict__ fp, float* __restrict__ tkv, int* __restrict__ tki)
{
    __shared__ float At[64 * 64];   // [kk][row]; reused as Sm [row][col] per tile
    __shared__ float Bt[64 * 64];   // [kk][col]
    __shared__ float Tv[64 * 33];   // top-32 values per row (stride 33: 2-way banks)
    __shared__ int   Ti[64 * 33];

    float* Sm = At;                 // alias: sim tile overwrites A chunk

    const int tid = threadIdx.x;
    const int w = tid >> 6, l = tid & 63;
    const int tr = tid >> 4, tc = tid & 15;
    const int r0 = blockIdx.x * 64;
    const int batch = r0 >> 12;               // / 4096
    const size_t bbase = (size_t)batch * N_;

    if (tid < 64) {
        #pragma unroll
        for (int s = 0; s < 32; ++s) { Tv[tid * 33 + s] = -1e30f; Ti[tid * 33 + s] = 0; }
    }
    float thr = -1e30f;   // current min of the 32 (owner lanes only)
    int minpos = 0;
    const int rot = (tid & 15) << 2;   // scan-phase column rotation (bank spread)

    for (int ct = 0; ct < 64; ++ct) {
        const int c0 = ct * 64;
        float4 acc0 = {0,0,0,0}, acc1 = {0,0,0,0}, acc2 = {0,0,0,0}, acc3 = {0,0,0,0};

        for (int kc = 0; kc < 4; ++kc) {
            __syncthreads();   // prior readers of At(Sm)/Bt are done
            #pragma unroll
            for (int i = 0; i < 4; ++i) {
                const int kloc = w * 16 + 4 * i;
                float4 a = *(const float4*)&fp[(size_t)(r0 + l) * D_ + C_ + kc * 64 + kloc];
                At[(kloc + 0) * 64 + l] = a.x;
                At[(kloc + 1) * 64 + l] = a.y;
                At[(kloc + 2) * 64 + l] = a.z;
                At[(kloc + 3) * 64 + l] = a.w;
                float4 b = *(const float4*)&fp[(bbase + c0 + l) * D_ + C_ + kc * 64 + kloc];
                Bt[(kloc + 0) * 64 + l] = b.x;
                Bt[(kloc + 1) * 64 + l] = b.y;
                Bt[(kloc + 2) * 64 + l] = b.z;
                Bt[(kloc + 3) * 64 + l] = b.w;
            }
            __syncthreads();
            #pragma unroll 8
            for (int kk = 0; kk < 64; ++kk) {
                float4 a = *(const float4*)&At[kk * 64 + 4 * tr];
                float4 b = *(const float4*)&Bt[kk * 64 + 4 * tc];
                acc0.x = fmaf(a.x, b.x, acc0.x); acc0.y = fmaf(a.x, b.y, acc0.y);
                acc0.z = fmaf(a.x, b.z, acc0.z); acc0.w = fmaf(a.x, b.w, acc0.w);
                acc1.x = fmaf(a.y, b.x, acc1.x); acc1.y = fmaf(a.y, b.y, acc1.y);
                acc1.z = fmaf(a.y, b.z, acc1.z); acc1.w = fmaf(a.y, b.w, acc1.w);
                acc2.x = fmaf(a.z, b.x, acc2.x); acc2.y = fmaf(a.z, b.y, acc2.y);
                acc2.z = fmaf(a.z, b.z, acc2.z); acc2.w = fmaf(a.z, b.w, acc2.w);
                acc3.x = fmaf(a.w, b.x, acc3.x); acc3.y = fmaf(a.w, b.y, acc3.y);
                acc3.z = fmaf(a.w, b.z, acc3.z); acc3.w = fmaf(a.w, b.w, acc3.w);
            }
        }

        __syncthreads();   // all At reads done before overwriting with Sm
        *(float4*)&Sm[(4 * tr + 0) * 64 + 4 * tc] = acc0;
        *(float4*)&Sm[(4 * tr + 1) * 64 + 4 * tc] = acc1;
        *(float4*)&Sm[(4 * tr + 2) * 64 + 4 * tc] = acc2;
        *(float4*)&Sm[(4 * tr + 3) * 64 + 4 * tc] = acc3;
        __syncthreads();

        // Streaming top-32 update: one owner lane per row, rotated column order.
        if (tid < 64) {
            const int base = tid * 64;
            const int tb = tid * 33;
            #pragma unroll 4
            for (int cc = 0; cc < 16; ++cc) {
                const int cidx = (4 * cc + rot) & 63;
                float4 v = *(const float4*)&Sm[base + cidx];
                #pragma unroll
                for (int j = 0; j < 4; ++j) {
                    float val = (j == 0) ? v.x : (j == 1) ? v.y : (j == 2) ? v.z : v.w;
                    if (val > thr) {   // strict > : earliest-kept on exact ties
                        Tv[tb + minpos] = val;
                        Ti[tb + minpos] = c0 + cidx + j;
                        float mn = 1e30f; int mp = 0;
                        for (int s = 0; s < 32; ++s) {
                            float u = Tv[tb + s];
                            if (u < mn) { mn = u; mp = s; }
                        }
                        thr = mn; minpos = mp;
                    }
                }
            }
        }
        // next tile's first __syncthreads orders scan reads vs restaging writes
    }

    __syncthreads();
    if (tid < 64) {
        const int row = r0 + tid;
        const int tb = tid * 33;
        #pragma unroll
        for (int s = 0; s < 32; ++s) {
            tkv[(size_t)row * 32 + s] = Tv[tb + s];
            tki[(size_t)row * 32 + s] = Ti[tb + s];
        }
    }
}

// ---------------------------------------------------------------------------
// Kernel 4: softmax over top-32 + gather feat + weighted sum -> out
// grid 32768: one block per row, one thread per channel.
// ---------------------------------------------------------------------------
__global__ __launch_bounds__(256) void k_out(
    const float* __restrict__ fp, const float* __restrict__ tkv,
    const int* __restrict__ tki, float* __restrict__ out)
{
    __shared__ float attn[32];
    __shared__ int   sid[32];
    const int row = blockIdx.x;
    const int batch = row >> 12;
    const int tid = threadIdx.x;

    if (tid < 32) {
        float v = tkv[(size_t)row * 32 + tid];
        float m = v;
        #pragma unroll
        for (int s = 16; s >= 1; s >>= 1) m = fmaxf(m, __shfl_xor(m, s));
        float e = expf(v - m);
        float sum = e;
        #pragma unroll
        for (int s = 16; s >= 1; s >>= 1) sum += __shfl_xor(sum, s);
        attn[tid] = e / sum;
        sid[tid]  = tki[(size_t)row * 32 + tid];
    }
    __syncthreads();

    const float* featb = fp + (size_t)batch * N_ * D_;
    float acc = 0.0f;
    #pragma unroll 8
    for (int k = 0; k < 32; ++k)
        acc = fmaf(attn[k], featb[(size_t)sid[k] * D_ + tid], acc);
    out[(size_t)row * C_ + tid] = acc;
}

// ---------------------------------------------------------------------------
extern "C" void kernel_launch(void* const* d_in, const int* in_sizes, int n_in,
                              void* d_out, int out_size, void* d_ws, size_t ws_size,
                              hipStream_t stream)
{
    const float* x    = (const float*)d_in[0];
    const float* W    = (const float*)d_in[1];
    const float* bias = (const float*)d_in[2];
    // d_in[3] = k (=32), compile-time constant here.

    float* fp  = (float*)d_ws;                      // ROWS * D_
    float* tkv = fp + (size_t)ROWS * D_;            // ROWS * 32
    int*   tki = (int*)(tkv + (size_t)ROWS * 32);   // ROWS * 32
    float* out = (float*)d_out;

    k_gemm_bias<<<dim3(D_ / 64, ROWS / 64), 256, 0, stream>>>(x, W, bias, fp);
    k_norm<<<ROWS / 4, 256, 0, stream>>>(fp);
    k_simtopk<<<ROWS / 64, 256, 0, stream>>>(fp, tkv, tki);
    k_out<<<ROWS, 256, 0, stream>>>(fp, tkv, tki, out);
}

// Round 3
// 2449.698 us; speedup vs baseline: 1.7053x; 1.1175x over previous
//
#include <hip/hip_runtime.h>
#include <math.h>

// Problem constants (B=8, N=4096, C=256, K=32)
constexpr int B_ = 8;
constexpr int N_ = 4096;
constexpr int C_ = 256;
constexpr int K_ = 32;
constexpr int D_ = 2 * C_;          // 512
constexpr int ROWS = B_ * N_;       // 32768

// ws layout:
//   fp  : float[ROWS * D_]   (64 MB)  feat_pos, feat = [:,0:256], pos = [:,256:512]
//   tkv : float[ROWS * 32]   (4 MB)
//   tki : int  [ROWS * 32]   (4 MB)

// ---------------------------------------------------------------------------
// Kernel 1: feat_pos = x @ W^T + bias   (fp32 tiled GEMM)  -- ~25 us, unchanged
// ---------------------------------------------------------------------------
__global__ __launch_bounds__(256, 4) void k_gemm_bias(
    const float* __restrict__ x, const float* __restrict__ W,
    const float* __restrict__ bias, float* __restrict__ fp)
{
    __shared__ float At[64 * 64];   // [kk][row]
    __shared__ float Bt[64 * 64];   // [kk][dcol]

    const int tid = threadIdx.x;
    const int w = tid >> 6, l = tid & 63;
    const int tr = tid >> 4, tc = tid & 15;
    const int d0 = blockIdx.x * 64;
    const int r0 = blockIdx.y * 64;

    float4 acc0 = {0,0,0,0}, acc1 = {0,0,0,0}, acc2 = {0,0,0,0}, acc3 = {0,0,0,0};

    for (int kc = 0; kc < 4; ++kc) {
        __syncthreads();
        #pragma unroll
        for (int i = 0; i < 4; ++i) {
            const int kloc = w * 16 + 4 * i;
            float4 a = *(const float4*)&x[(size_t)(r0 + l) * C_ + kc * 64 + kloc];
            At[(kloc + 0) * 64 + l] = a.x;
            At[(kloc + 1) * 64 + l] = a.y;
            At[(kloc + 2) * 64 + l] = a.z;
            At[(kloc + 3) * 64 + l] = a.w;
            float4 b = *(const float4*)&W[(size_t)(d0 + l) * C_ + kc * 64 + kloc];
            Bt[(kloc + 0) * 64 + l] = b.x;
            Bt[(kloc + 1) * 64 + l] = b.y;
            Bt[(kloc + 2) * 64 + l] = b.z;
            Bt[(kloc + 3) * 64 + l] = b.w;
        }
        __syncthreads();
        #pragma unroll 8
        for (int kk = 0; kk < 64; ++kk) {
            float4 a = *(const float4*)&At[kk * 64 + 4 * tr];
            float4 b = *(const float4*)&Bt[kk * 64 + 4 * tc];
            acc0.x = fmaf(a.x, b.x, acc0.x); acc0.y = fmaf(a.x, b.y, acc0.y);
            acc0.z = fmaf(a.x, b.z, acc0.z); acc0.w = fmaf(a.x, b.w, acc0.w);
            acc1.x = fmaf(a.y, b.x, acc1.x); acc1.y = fmaf(a.y, b.y, acc1.y);
            acc1.z = fmaf(a.y, b.z, acc1.z); acc1.w = fmaf(a.y, b.w, acc1.w);
            acc2.x = fmaf(a.z, b.x, acc2.x); acc2.y = fmaf(a.z, b.y, acc2.y);
            acc2.z = fmaf(a.z, b.z, acc2.z); acc2.w = fmaf(a.z, b.w, acc2.w);
            acc3.x = fmaf(a.w, b.x, acc3.x); acc3.y = fmaf(a.w, b.y, acc3.y);
            acc3.z = fmaf(a.w, b.z, acc3.z); acc3.w = fmaf(a.w, b.w, acc3.w);
        }
    }

    float4 bv = *(const float4*)&bias[d0 + 4 * tc];
    float4 o;
    o.x = acc0.x + bv.x; o.y = acc0.y + bv.y; o.z = acc0.z + bv.z; o.w = acc0.w + bv.w;
    *(float4*)&fp[(size_t)(r0 + 4 * tr + 0) * D_ + d0 + 4 * tc] = o;
    o.x = acc1.x + bv.x; o.y = acc1.y + bv.y; o.z = acc1.z + bv.z; o.w = acc1.w + bv.w;
    *(float4*)&fp[(size_t)(r0 + 4 * tr + 1) * D_ + d0 + 4 * tc] = o;
    o.x = acc2.x + bv.x; o.y = acc2.y + bv.y; o.z = acc2.z + bv.z; o.w = acc2.w + bv.w;
    *(float4*)&fp[(size_t)(r0 + 4 * tr + 2) * D_ + d0 + 4 * tc] = o;
    o.x = acc3.x + bv.x; o.y = acc3.y + bv.y; o.z = acc3.z + bv.z; o.w = acc3.w + bv.w;
    *(float4*)&fp[(size_t)(r0 + 4 * tr + 3) * D_ + d0 + 4 * tc] = o;
}

// ---------------------------------------------------------------------------
// Kernel 2: normalize pos rows in place. One wave per row.
// ---------------------------------------------------------------------------
__global__ __launch_bounds__(256) void k_norm(float* __restrict__ fp)
{
    const int w = threadIdx.x >> 6, l = threadIdx.x & 63;
    const int row = blockIdx.x * 4 + w;
    float* p = &fp[(size_t)row * D_ + C_];
    float4 v = *(float4*)&p[4 * l];
    float s = v.x * v.x + v.y * v.y + v.z * v.z + v.w * v.w;
    #pragma unroll
    for (int m = 1; m < 64; m <<= 1) s += __shfl_xor(s, m);
    float scale = 1.0f / fmaxf(sqrtf(s), 1e-12f);
    v.x *= scale; v.y *= scale; v.z *= scale; v.w *= scale;
    *(float4*)&p[4 * l] = v;
}

// ---------------------------------------------------------------------------
// Kernel 3: fused sim (pos @ pos^T per batch, fp32) + register-resident top-32.
// 128x128 tile, 512 threads (8 waves), 4x8 acc/thread. Each wave owns 16 rows;
// row's top-32 lives in one wave-half (32 lanes) x 8 reg slots. Scan is
// all-wave parallel: ballot candidates > running min, shuffle-argmin eviction.
// Tie rules (strict >, evict equal-min with larger idx) match stable top_k.
// ---------------------------------------------------------------------------
__global__ __launch_bounds__(512, 2) void k_simtopk(
    const float* __restrict__ fp, float* __restrict__ tkv, int* __restrict__ tki)
{
    __shared__ float At[64 * 128];      // [kk][row]   32 KB
    __shared__ float Bt[64 * 128];      // [kk][col]   32 KB
    __shared__ float Sm[128 * 132];     // sim tile, stride 132 (66 KB)

    const int tid  = threadIdx.x;
    const int lane = tid & 63;
    const int wave = tid >> 6;          // 0..7
    const int half = lane >> 5;         // 0/1
    const int hl   = lane & 31;         // lane within half
    const int tr   = tid >> 4;          // 0..31 -> 4-row group
    const int tc   = tid & 15;          // 0..15 -> 8-col group
    const int r0   = blockIdx.x * 128;
    const int batch = r0 >> 12;
    const size_t bbase = (size_t)batch * N_;

    const int srow = tid & 127;         // staging row/col owner
    const int kq   = tid >> 7;          // 0..3 k-quarter

    // Per-wave top-k register state: slot p holds rows wave*16 + 2p + half.
    float sval[8]; int sidx[8];
    float mv[8]; int ml[8]; int mi[8];
    #pragma unroll
    for (int p = 0; p < 8; ++p) {
        sval[p] = -1e30f; sidx[p] = 0; mv[p] = -1e30f; ml[p] = half << 5; mi[p] = 0;
    }

    for (int ct = 0; ct < 32; ++ct) {
        const int c0 = ct * 128;
        float acc[4][8];
        #pragma unroll
        for (int i = 0; i < 4; ++i)
            #pragma unroll
            for (int j = 0; j < 8; ++j) acc[i][j] = 0.0f;

        for (int kc = 0; kc < 4; ++kc) {
            __syncthreads();            // prior readers of At/Bt (and prev scan) done
            #pragma unroll
            for (int j = 0; j < 4; ++j) {
                const int kl = kq * 16 + j * 4;
                float4 a = *(const float4*)&fp[(size_t)(r0 + srow) * D_ + C_ + kc * 64 + kl];
                At[(kl + 0) * 128 + srow] = a.x;
                At[(kl + 1) * 128 + srow] = a.y;
                At[(kl + 2) * 128 + srow] = a.z;
                At[(kl + 3) * 128 + srow] = a.w;
                float4 b = *(const float4*)&fp[(bbase + c0 + srow) * D_ + C_ + kc * 64 + kl];
                Bt[(kl + 0) * 128 + srow] = b.x;
                Bt[(kl + 1) * 128 + srow] = b.y;
                Bt[(kl + 2) * 128 + srow] = b.z;
                Bt[(kl + 3) * 128 + srow] = b.w;
            }
            __syncthreads();
            #pragma unroll 4
            for (int kk = 0; kk < 64; ++kk) {
                float4 av = *(const float4*)&At[kk * 128 + 4 * tr];
                float4 b0 = *(const float4*)&Bt[kk * 128 + 8 * tc];
                float4 b1 = *(const float4*)&Bt[kk * 128 + 8 * tc + 4];
                const float ar[4] = {av.x, av.y, av.z, av.w};
                const float br[8] = {b0.x, b0.y, b0.z, b0.w, b1.x, b1.y, b1.z, b1.w};
                #pragma unroll
                for (int i = 0; i < 4; ++i)
                    #pragma unroll
                    for (int j = 0; j < 8; ++j)
                        acc[i][j] = fmaf(ar[i], br[j], acc[i][j]);
            }
        }

        // Write sim tile (ordering vs prev scan guaranteed by kc-loop barriers)
        #pragma unroll
        for (int i = 0; i < 4; ++i) {
            float4 o0 = {acc[i][0], acc[i][1], acc[i][2], acc[i][3]};
            float4 o1 = {acc[i][4], acc[i][5], acc[i][6], acc[i][7]};
            *(float4*)&Sm[(4 * tr + i) * 132 + 8 * tc]     = o0;
            *(float4*)&Sm[(4 * tr + i) * 132 + 8 * tc + 4] = o1;
        }
        __syncthreads();

        // ---- parallel scan: wave handles its 16 rows (2 per pass, one per half)
        #pragma unroll
        for (int p = 0; p < 8; ++p) {
            const int rbase = (wave * 16 + 2 * p + half) * 132;
            int g0 = 0;
            if (ct == 0) {
                // direct-fill slots from cols 0..31
                sval[p] = Sm[rbase + hl];
                sidx[p] = hl;
                float rv = sval[p]; int ri = sidx[p]; int rl = lane;
                #pragma unroll
                for (int s = 1; s < 32; s <<= 1) {
                    float ov = __shfl_xor(rv, s);
                    int   oi = __shfl_xor(ri, s);
                    int   ol = __shfl_xor(rl, s);
                    if (ov < rv || (ov == rv && oi > ri)) { rv = ov; ri = oi; rl = ol; }
                }
                mv[p] = rv; mi[p] = ri; ml[p] = rl;
                g0 = 1;
            }
            for (int g = g0; g < 4; ++g) {
                const int col = g * 32 + hl;
                float v  = Sm[rbase + col];
                int   vc = c0 + col;
                while (true) {
                    unsigned long long bm = __ballot(v > mv[p]);
                    unsigned mh = half ? (unsigned)(bm >> 32) : (unsigned)(bm & 0xffffffffu);
                    if (!mh) break;
                    const int srcl = (__ffs(mh) - 1) + (half << 5);   // lowest col first
                    const float cv = __shfl(v, srcl);
                    const int   cc = __shfl(vc, srcl);
                    if (lane == ml[p]) { sval[p] = cv; sidx[p] = cc; }  // evict min
                    if (lane == srcl) v = -1e30f;                        // consume
                    float rv = sval[p]; int ri = sidx[p]; int rl = lane;
                    #pragma unroll
                    for (int s = 1; s < 32; s <<= 1) {
                        float ov = __shfl_xor(rv, s);
                        int   oi = __shfl_xor(ri, s);
                        int   ol = __shfl_xor(rl, s);
                        if (ov < rv || (ov == rv && oi > ri)) { rv = ov; ri = oi; rl = ol; }
                    }
                    mv[p] = rv; mi[p] = ri; ml[p] = rl;
                }
            }
        }
        // next tile's first barrier orders this scan vs restaging/Sm overwrite
    }

    // Writeout: entry hl of each owned row (order-free: softmax+sum is invariant)
    #pragma unroll
    for (int p = 0; p < 8; ++p) {
        const int row = r0 + wave * 16 + 2 * p + half;
        tkv[(size_t)row * 32 + hl] = sval[p];
        tki[(size_t)row * 32 + hl] = sidx[p];
    }
}

// ---------------------------------------------------------------------------
// Kernel 4: softmax over top-32 + gather feat + weighted sum -> out
// ---------------------------------------------------------------------------
__global__ __launch_bounds__(256) void k_out(
    const float* __restrict__ fp, const float* __restrict__ tkv,
    const int* __restrict__ tki, float* __restrict__ out)
{
    __shared__ float attn[32];
    __shared__ int   sid[32];
    const int row = blockIdx.x;
    const int batch = row >> 12;
    const int tid = threadIdx.x;

    if (tid < 32) {
        float v = tkv[(size_t)row * 32 + tid];
        float m = v;
        #pragma unroll
        for (int s = 16; s >= 1; s >>= 1) m = fmaxf(m, __shfl_xor(m, s));
        float e = expf(v - m);
        float sum = e;
        #pragma unroll
        for (int s = 16; s >= 1; s >>= 1) sum += __shfl_xor(sum, s);
        attn[tid] = e / sum;
        sid[tid]  = tki[(size_t)row * 32 + tid];
    }
    __syncthreads();

    const float* featb = fp + (size_t)batch * N_ * D_;
    float acc = 0.0f;
    #pragma unroll 8
    for (int k = 0; k < 32; ++k)
        acc = fmaf(attn[k], featb[(size_t)sid[k] * D_ + tid], acc);
    out[(size_t)row * C_ + tid] = acc;
}

// ---------------------------------------------------------------------------
extern "C" void kernel_launch(void* const* d_in, const int* in_sizes, int n_in,
                              void* d_out, int out_size, void* d_ws, size_t ws_size,
                              hipStream_t stream)
{
    const float* x    = (const float*)d_in[0];
    const float* W    = (const float*)d_in[1];
    const float* bias = (const float*)d_in[2];
    // d_in[3] = k (=32), compile-time constant here.

    float* fp  = (float*)d_ws;                      // ROWS * D_
    float* tkv = fp + (size_t)ROWS * D_;            // ROWS * 32
    int*   tki = (int*)(tkv + (size_t)ROWS * 32);   // ROWS * 32
    float* out = (float*)d_out;

    k_gemm_bias<<<dim3(D_ / 64, ROWS / 64), 256, 0, stream>>>(x, W, bias, fp);
    k_norm<<<ROWS / 4, 256, 0, stream>>>(fp);
    k_simtopk<<<ROWS / 128, 512, 0, stream>>>(fp, tkv, tki);
    k_out<<<ROWS, 256, 0, stream>>>(fp, tkv, tki, out);
}